// Round 1
// baseline (473.814 us; speedup 1.0000x reference)
//
#include <hip/hip_runtime.h>
#include <hip/hip_bf16.h>

// Problem constants (from reference): N=20000 nodes, K=32 nbrs, C=128, H=256
#define NN   20000
#define KNN  32
#define CIN  128
#define HD   256
#define EE   (NN * KNN)      // 640000 edges
#define MTILE 64             // edge rows per block = 2 full nodes (K=32)
#define LSTR  264            // LDS row stride in bf16 elems (256 + 8 pad -> 4-bank shift/row)

typedef __bf16 bf16x8_t __attribute__((ext_vector_type(8)));
typedef __bf16 bf16x4_t __attribute__((ext_vector_type(4)));
typedef float  f32x4_t  __attribute__((ext_vector_type(4)));

// Transpose + cast weights to bf16, layout WT[n*256 + k] so that a B-fragment
// (lane holds B[k=quad*8+j][n=lane&15]) is one contiguous 16B load.
__global__ void ec_prep_weights(const float* __restrict__ W1, const float* __restrict__ W2,
                                __bf16* __restrict__ W1T, __bf16* __restrict__ W2T) {
    int idx = blockIdx.x * 256 + threadIdx.x;   // 0..65535, coalesced read
    int k = idx >> 8;
    int n = idx & 255;
    W1T[n * 256 + k] = (__bf16)W1[idx];         // W1 is [k][n] row-major: idx = k*256+n
    W2T[n * 256 + k] = (__bf16)W2[idx];
}

__global__ __launch_bounds__(256, 2) void ec_main(
    const float* __restrict__ nf,        // [NN][CIN]
    const int*   __restrict__ senders,   // [EE]
    const __bf16* __restrict__ W1T,      // [256][256]  (n-major, k contiguous)
    const __bf16* __restrict__ W2T,      // [256][256]
    const float* __restrict__ b1,        // [HD]
    const float* __restrict__ b2,        // [HD]
    float* __restrict__ out)             // [NN][HD]
{
    __shared__ __bf16 sA[MTILE * LSTR];  // edge features [64][256] (+pad)
    __shared__ __bf16 sH[MTILE * LSTR];  // relu(h1)      [64][256] (+pad)

    const int tid  = threadIdx.x;
    const int lane = tid & 63;
    const int wave = tid >> 6;           // 0..3 -> column slice wave*64
    const int blk  = blockIdx.x;
    const int qrow = lane >> 4;          // quad 0..3
    const int lcol = lane & 15;

    // ---- Stage A: A[m][0:128] = x_v ; A[m][128:256] = x_vp - x_v  (bf16) ----
    {
        const int row  = tid >> 2;            // 0..63
        const int part = tid & 3;             // 32-col chunk within each 128 half
        const int e    = blk * MTILE + row;
        const int recv = blk * 2 + (row >> 5);
        const int send = senders[e];
        const float4* vrow = (const float4*)(nf + (size_t)recv * CIN) + part * 8;
        const float4* urow = (const float4*)(nf + (size_t)send * CIN) + part * 8;
        __bf16* a0 = sA + row * LSTR + part * 32;
        __bf16* a1 = a0 + CIN;
#pragma unroll
        for (int i = 0; i < 8; ++i) {
            float4 v = vrow[i];
            float4 u = urow[i];
            bf16x4_t pv = { (__bf16)v.x, (__bf16)v.y, (__bf16)v.z, (__bf16)v.w };
            bf16x4_t pd = { (__bf16)(u.x - v.x), (__bf16)(u.y - v.y),
                            (__bf16)(u.z - v.z), (__bf16)(u.w - v.w) };
            *(bf16x4_t*)(a0 + i * 4) = pv;
            *(bf16x4_t*)(a1 + i * 4) = pd;
        }
    }
    __syncthreads();

    f32x4_t acc[4][4];

    // ---- GEMM1: h1 = relu(A @ W1 + b1), written to sH as bf16 ----
#pragma unroll
    for (int mi = 0; mi < 4; ++mi)
#pragma unroll
        for (int ni = 0; ni < 4; ++ni)
            acc[mi][ni] = (f32x4_t){0.f, 0.f, 0.f, 0.f};

#pragma unroll
    for (int kt = 0; kt < 8; ++kt) {
        bf16x8_t af[4], bfr[4];
#pragma unroll
        for (int mi = 0; mi < 4; ++mi)
            af[mi] = *(const bf16x8_t*)(sA + (mi * 16 + lcol) * LSTR + kt * 32 + qrow * 8);
#pragma unroll
        for (int ni = 0; ni < 4; ++ni) {
            int n = wave * 64 + ni * 16 + lcol;
            bfr[ni] = *(const bf16x8_t*)(W1T + n * 256 + kt * 32 + qrow * 8);
        }
#pragma unroll
        for (int mi = 0; mi < 4; ++mi)
#pragma unroll
            for (int ni = 0; ni < 4; ++ni)
                acc[mi][ni] = __builtin_amdgcn_mfma_f32_16x16x32_bf16(
                    af[mi], bfr[ni], acc[mi][ni], 0, 0, 0);
    }

    // epilogue 1: +b1, relu, cast bf16 -> sH  (C/D layout: col=lane&15, row=quad*4+reg)
#pragma unroll
    for (int ni = 0; ni < 4; ++ni) {
        int col = wave * 64 + ni * 16 + lcol;
        float bias = b1[col];
#pragma unroll
        for (int mi = 0; mi < 4; ++mi) {
#pragma unroll
            for (int r = 0; r < 4; ++r) {
                int m = mi * 16 + qrow * 4 + r;
                float v = acc[mi][ni][r] + bias;
                v = v > 0.f ? v : 0.f;
                sH[m * LSTR + col] = (__bf16)v;
            }
        }
    }
    __syncthreads();

    // ---- GEMM2: h2 = sH @ W2 ----
#pragma unroll
    for (int mi = 0; mi < 4; ++mi)
#pragma unroll
        for (int ni = 0; ni < 4; ++ni)
            acc[mi][ni] = (f32x4_t){0.f, 0.f, 0.f, 0.f};

#pragma unroll
    for (int kt = 0; kt < 8; ++kt) {
        bf16x8_t af[4], bfr[4];
#pragma unroll
        for (int mi = 0; mi < 4; ++mi)
            af[mi] = *(const bf16x8_t*)(sH + (mi * 16 + lcol) * LSTR + kt * 32 + qrow * 8);
#pragma unroll
        for (int ni = 0; ni < 4; ++ni) {
            int n = wave * 64 + ni * 16 + lcol;
            bfr[ni] = *(const bf16x8_t*)(W2T + n * 256 + kt * 32 + qrow * 8);
        }
#pragma unroll
        for (int mi = 0; mi < 4; ++mi)
#pragma unroll
            for (int ni = 0; ni < 4; ++ni)
                acc[mi][ni] = __builtin_amdgcn_mfma_f32_16x16x32_bf16(
                    af[mi], bfr[ni], acc[mi][ni], 0, 0, 0);
    }

    // ---- epilogue 2: per-node max over 32 rows, +b2 (exact after max), store ----
    // node 0 = rows 0..31 (mi 0,1), node 1 = rows 32..63 (mi 2,3)
#pragma unroll
    for (int ni = 0; ni < 4; ++ni) {
        int col = wave * 64 + ni * 16 + lcol;
#pragma unroll
        for (int node = 0; node < 2; ++node) {
            float mx = -3.402823466e38f;
#pragma unroll
            for (int mi = 0; mi < 2; ++mi)
#pragma unroll
                for (int r = 0; r < 4; ++r)
                    mx = fmaxf(mx, acc[node * 2 + mi][ni][r]);
            // rows covered so far: quad*4+r and 16+quad*4+r; reduce across quads
            mx = fmaxf(mx, __shfl_xor(mx, 16, 64));
            mx = fmaxf(mx, __shfl_xor(mx, 32, 64));
            if (qrow == 0) {
                out[(size_t)(blk * 2 + node) * HD + col] = mx + b2[col];
            }
        }
    }
}

extern "C" void kernel_launch(void* const* d_in, const int* in_sizes, int n_in,
                              void* d_out, int out_size, void* d_ws, size_t ws_size,
                              hipStream_t stream) {
    const float* nf      = (const float*)d_in[0];
    const int*   senders = (const int*)d_in[1];
    // d_in[2] = receivers: implicit (repeat(arange(N), K)), unused
    const float* W1 = (const float*)d_in[3];
    const float* b1 = (const float*)d_in[4];
    const float* W2 = (const float*)d_in[5];
    const float* b2 = (const float*)d_in[6];

    __bf16* W1T = (__bf16*)d_ws;           // 256*256 bf16 = 128 KB
    __bf16* W2T = W1T + 256 * 256;         // next 128 KB

    ec_prep_weights<<<256, 256, 0, stream>>>(W1, W2, W1T, W2T);
    ec_main<<<EE / MTILE, 256, 0, stream>>>(nf, senders, W1T, W2T, b1, b2, (float*)d_out);
}

// Round 2
// 442.125 us; speedup vs baseline: 1.0717x; 1.0717x over previous
//
#include <hip/hip_runtime.h>
#include <hip/hip_bf16.h>

// Problem constants (from reference): N=20000 nodes, K=32 nbrs, C=128, H=256
#define NN   20000
#define KNN  32
#define CIN  128
#define HD   256
#define EE   (NN * KNN)      // 640000 edges
#define MTILE 64             // edge rows per block = 2 full nodes (K=32)
#define LSTR  264            // LDS row stride in bf16 elems (256 + 8 pad)

typedef __bf16 bf16x8_t __attribute__((ext_vector_type(8)));
typedef __bf16 bf16x4_t __attribute__((ext_vector_type(4)));
typedef float  f32x4_t  __attribute__((ext_vector_type(4)));

// Transpose + cast weights to bf16, layout WT[n*256 + k]: a W-fragment
// (lane holds W[k=quad*8+j][n=lane&15]) is one contiguous 16B load.
__global__ void ec_prep_weights(const float* __restrict__ W1, const float* __restrict__ W2,
                                __bf16* __restrict__ W1T, __bf16* __restrict__ W2T) {
    int idx = blockIdx.x * 256 + threadIdx.x;   // 0..65535, coalesced read
    int k = idx >> 8;
    int n = idx & 255;
    W1T[n * 256 + k] = (__bf16)W1[idx];         // W1 is [k][n] row-major: idx = k*256+n
    W2T[n * 256 + k] = (__bf16)W2[idx];
}

// Single LDS buffer (33792 B) aliased for E (edge features) then H=relu(EW1+b1):
// 4 blocks/CU instead of 2 -> 16 waves/CU for latency hiding.
__global__ __launch_bounds__(256, 4) void ec_main(
    const float* __restrict__ nf,        // [NN][CIN]
    const int*   __restrict__ senders,   // [EE]
    const __bf16* __restrict__ W1T,      // [256][256]  (n-major, k contiguous)
    const __bf16* __restrict__ W2T,      // [256][256]
    const float* __restrict__ b1,        // [HD]
    const float* __restrict__ b2,        // [HD]
    float* __restrict__ out)             // [NN][HD]
{
    __shared__ __bf16 sB[MTILE * LSTR];  // edge features, later relu(h1)

    const int tid  = threadIdx.x;
    const int lane = tid & 63;
    const int wave = tid >> 6;           // 0..3
    const int blk  = blockIdx.x;
    const int qrow = lane >> 4;          // quad 0..3
    const int lcol = lane & 15;

    // ---- Stage E: E[m][0:128] = x_v ; E[m][128:256] = x_vp - x_v  (bf16) ----
    {
        const int row  = tid >> 2;            // 0..63
        const int part = tid & 3;             // 32-col chunk within each 128 half
        const int e    = blk * MTILE + row;
        const int recv = blk * 2 + (row >> 5);
        const int send = senders[e];
        const float4* vrow = (const float4*)(nf + (size_t)recv * CIN) + part * 8;
        const float4* urow = (const float4*)(nf + (size_t)send * CIN) + part * 8;
        __bf16* a0 = sB + row * LSTR + part * 32;
        __bf16* a1 = a0 + CIN;
#pragma unroll
        for (int i = 0; i < 8; ++i) {
            float4 v = vrow[i];
            float4 u = urow[i];
            bf16x4_t pv = { (__bf16)v.x, (__bf16)v.y, (__bf16)v.z, (__bf16)v.w };
            bf16x4_t pd = { (__bf16)(u.x - v.x), (__bf16)(u.y - v.y),
                            (__bf16)(u.z - v.z), (__bf16)(u.w - v.w) };
            *(bf16x4_t*)(a0 + i * 4) = pv;
            *(bf16x4_t*)(a1 + i * 4) = pd;
        }
    }
    __syncthreads();

    f32x4_t acc[4][4];

    // ---- GEMM1 (operand-swapped): D = W1T_slice · E^T = H^T tiles ----
    // A-frag: A[i=lcol][k=qrow*8+j] = W1T[(wave*64+mi*16+lcol)*256 + k]
    // B-frag: B[k=qrow*8+j][jc=lcol] = E[ni*16+lcol][k]   (same read as unswapped A-frag)
    // D tile (mi,ni): row = H-feature (wave*64+mi*16+qrow*4+r), col = edge (ni*16+lcol)
#pragma unroll
    for (int mi = 0; mi < 4; ++mi)
#pragma unroll
        for (int ni = 0; ni < 4; ++ni)
            acc[mi][ni] = (f32x4_t){0.f, 0.f, 0.f, 0.f};

#pragma unroll
    for (int kt = 0; kt < 8; ++kt) {
        bf16x8_t wf[4], ef[4];
#pragma unroll
        for (int mi = 0; mi < 4; ++mi) {
            int n = wave * 64 + mi * 16 + lcol;
            wf[mi] = *(const bf16x8_t*)(W1T + n * 256 + kt * 32 + qrow * 8);
        }
#pragma unroll
        for (int ni = 0; ni < 4; ++ni)
            ef[ni] = *(const bf16x8_t*)(sB + (ni * 16 + lcol) * LSTR + kt * 32 + qrow * 8);
#pragma unroll
        for (int mi = 0; mi < 4; ++mi)
#pragma unroll
            for (int ni = 0; ni < 4; ++ni)
                acc[mi][ni] = __builtin_amdgcn_mfma_f32_16x16x32_bf16(
                    wf[mi], ef[ni], acc[mi][ni], 0, 0, 0);
    }

    __syncthreads();   // all waves done READING sB before we overwrite it with H

    // epilogue 1: +b1, relu, packed bf16x4 write of 4 consecutive features of one edge row
#pragma unroll
    for (int mi = 0; mi < 4; ++mi) {
        int fbase = wave * 64 + mi * 16 + qrow * 4;
        float4 bias = *(const float4*)(b1 + fbase);
#pragma unroll
        for (int ni = 0; ni < 4; ++ni) {
            int m = ni * 16 + lcol;            // edge row
            float v0 = acc[mi][ni][0] + bias.x;
            float v1 = acc[mi][ni][1] + bias.y;
            float v2 = acc[mi][ni][2] + bias.z;
            float v3 = acc[mi][ni][3] + bias.w;
            bf16x4_t h = { (__bf16)(v0 > 0.f ? v0 : 0.f),
                           (__bf16)(v1 > 0.f ? v1 : 0.f),
                           (__bf16)(v2 > 0.f ? v2 : 0.f),
                           (__bf16)(v3 > 0.f ? v3 : 0.f) };
            *(bf16x4_t*)(sB + m * LSTR + fbase) = h;
        }
    }
    __syncthreads();

    // ---- GEMM2 (unswapped): D = H · W2  ----
    // A-frag: A[m=lcol][k] = sB[(mi*16+lcol)*LSTR + k]
    // B-frag: B[k][n=lcol] = W2T[(wave*64+ni*16+lcol)*256 + k]
    // D tile: col = out-feature (lane&15), row = edge (quad*4+reg)
#pragma unroll
    for (int mi = 0; mi < 4; ++mi)
#pragma unroll
        for (int ni = 0; ni < 4; ++ni)
            acc[mi][ni] = (f32x4_t){0.f, 0.f, 0.f, 0.f};

#pragma unroll
    for (int kt = 0; kt < 8; ++kt) {
        bf16x8_t af[4], bfr[4];
#pragma unroll
        for (int mi = 0; mi < 4; ++mi)
            af[mi] = *(const bf16x8_t*)(sB + (mi * 16 + lcol) * LSTR + kt * 32 + qrow * 8);
#pragma unroll
        for (int ni = 0; ni < 4; ++ni) {
            int n = wave * 64 + ni * 16 + lcol;
            bfr[ni] = *(const bf16x8_t*)(W2T + n * 256 + kt * 32 + qrow * 8);
        }
#pragma unroll
        for (int mi = 0; mi < 4; ++mi)
#pragma unroll
            for (int ni = 0; ni < 4; ++ni)
                acc[mi][ni] = __builtin_amdgcn_mfma_f32_16x16x32_bf16(
                    af[mi], bfr[ni], acc[mi][ni], 0, 0, 0);
    }

    // ---- epilogue 2: per-node max over 32 edge rows, +b2 (exact after max), store ----
    // node 0 = rows 0..31 (mi 0,1), node 1 = rows 32..63 (mi 2,3)
#pragma unroll
    for (int ni = 0; ni < 4; ++ni) {
        int col = wave * 64 + ni * 16 + lcol;
#pragma unroll
        for (int node = 0; node < 2; ++node) {
            float mx = -3.402823466e38f;
#pragma unroll
            for (int mi = 0; mi < 2; ++mi)
#pragma unroll
                for (int r = 0; r < 4; ++r)
                    mx = fmaxf(mx, acc[node * 2 + mi][ni][r]);
            // rows covered: quad*4+r and 16+quad*4+r; reduce across quads
            mx = fmaxf(mx, __shfl_xor(mx, 16, 64));
            mx = fmaxf(mx, __shfl_xor(mx, 32, 64));
            if (qrow == 0) {
                out[(size_t)(blk * 2 + node) * HD + col] = mx + b2[col];
            }
        }
    }
}

extern "C" void kernel_launch(void* const* d_in, const int* in_sizes, int n_in,
                              void* d_out, int out_size, void* d_ws, size_t ws_size,
                              hipStream_t stream) {
    const float* nf      = (const float*)d_in[0];
    const int*   senders = (const int*)d_in[1];
    // d_in[2] = receivers: implicit (repeat(arange(N), K)), unused
    const float* W1 = (const float*)d_in[3];
    const float* b1 = (const float*)d_in[4];
    const float* W2 = (const float*)d_in[5];
    const float* b2 = (const float*)d_in[6];

    __bf16* W1T = (__bf16*)d_ws;           // 256*256 bf16 = 128 KB
    __bf16* W2T = W1T + 256 * 256;         // next 128 KB

    ec_prep_weights<<<256, 256, 0, stream>>>(W1, W2, W1T, W2T);
    ec_main<<<EE / MTILE, 256, 0, stream>>>(nf, senders, W1T, W2T, b1, b2, (float*)d_out);
}

// Round 3
// 440.099 us; speedup vs baseline: 1.0766x; 1.0046x over previous
//
#include <hip/hip_runtime.h>
#include <hip/hip_bf16.h>

// Problem constants: N=20000 nodes, K=32 nbrs, C=128, H=256
#define NN    20000
#define KNN   32
#define CIN   128
#define HD    256
#define EE    (NN * KNN)       // 640000 edges
#define MTILE 64               // edge rows per tile = 2 full nodes
#define LSTR  264              // LDS row stride (bf16 elems), 256+8 pad
#define TPB   5                // M-tiles per block
#define NBLK  (EE / (MTILE * TPB))   // 2000 blocks

typedef __bf16 bf16x8_t __attribute__((ext_vector_type(8)));
typedef __bf16 bf16x4_t __attribute__((ext_vector_type(4)));
typedef float  f32x4_t  __attribute__((ext_vector_type(4)));

// Transpose + cast weights to bf16, layout WT[n*256 + k]: one fragment
// (lane holds W[k=quad*8+j][n=lane&15]) = one contiguous 16B load.
__global__ void ec_prep_weights(const float* __restrict__ W1, const float* __restrict__ W2,
                                __bf16* __restrict__ W1T, __bf16* __restrict__ W2T) {
    int idx = blockIdx.x * 256 + threadIdx.x;
    int k = idx >> 8, n = idx & 255;
    W1T[n * 256 + k] = (__bf16)W1[idx];   // W is [k][n] row-major: idx = k*256+n
    W2T[n * 256 + k] = (__bf16)W2[idx];
}

// 1 block/CU (high VGPR), W1+W2 fragments register-resident, 5 tiles/block,
// next tile's gather overlapped with GEMM2's K-loop.
__global__ __launch_bounds__(256, 1) void ec_main(
    const float* __restrict__ nf,        // [NN][CIN] fp32
    const int*   __restrict__ senders,   // [EE]
    const __bf16* __restrict__ W1T,      // [256 n][256 k]
    const __bf16* __restrict__ W2T,      // [256 n][256 k]
    const float* __restrict__ b1,
    const float* __restrict__ b2,
    float* __restrict__ out)             // [NN][HD] fp32
{
    __shared__ __bf16 sE[2 * MTILE * LSTR];  // double-buffered edge features
    __shared__ __bf16 sH[MTILE * LSTR];      // relu(h1)

    const int tid  = threadIdx.x;
    const int lane = tid & 63;
    const int wave = tid >> 6;
    const int qrow = lane >> 4;
    const int lcol = lane & 15;
    const int blk  = blockIdx.x;
    const int srow  = tid >> 2;   // staging: edge row 0..63
    const int spart = tid & 3;    // staging: 32-elem chunk within each 128-half

    // ---- W fragments: register-resident for the whole kernel ----
    bf16x8_t w1f[8][4], w2f[8][4];   // [kt][tile-of-16-cols]
#pragma unroll
    for (int kt = 0; kt < 8; ++kt)
#pragma unroll
        for (int mi = 0; mi < 4; ++mi) {
            int n = wave * 64 + mi * 16 + lcol;
            w1f[kt][mi] = *(const bf16x8_t*)(W1T + n * 256 + kt * 32 + qrow * 8);
            w2f[kt][mi] = *(const bf16x8_t*)(W2T + n * 256 + kt * 32 + qrow * 8);
        }
    float4 bias1[4];
#pragma unroll
    for (int mi = 0; mi < 4; ++mi)
        bias1[mi] = *(const float4*)(b1 + wave * 64 + mi * 16 + qrow * 4);

    // ---- gather tile 0 into sE[0] ----
    {
        int g = blk * TPB;
        int send = senders[g * MTILE + srow];
        int recv = g * 2 + (srow >> 5);
        const float4* vr = (const float4*)(nf + (size_t)recv * CIN) + spart * 8;
        const float4* ur = (const float4*)(nf + (size_t)send * CIN) + spart * 8;
        __bf16* a0 = sE + srow * LSTR + spart * 32;
#pragma unroll
        for (int i = 0; i < 8; ++i) {
            float4 v = vr[i], u = ur[i];
            bf16x4_t pv = { (__bf16)v.x, (__bf16)v.y, (__bf16)v.z, (__bf16)v.w };
            bf16x4_t pd = { (__bf16)(u.x - v.x), (__bf16)(u.y - v.y),
                            (__bf16)(u.z - v.z), (__bf16)(u.w - v.w) };
            *(bf16x4_t*)(a0 + i * 4)       = pv;
            *(bf16x4_t*)(a0 + CIN + i * 4) = pd;
        }
    }
    __syncthreads();

    int cur = 0;
    for (int t = 0; t < TPB; ++t) {
        const __bf16* sEc = sE + cur * (MTILE * LSTR);

        f32x4_t acc[4][4];
#pragma unroll
        for (int mi = 0; mi < 4; ++mi)
#pragma unroll
            for (int ni = 0; ni < 4; ++ni)
                acc[mi][ni] = (f32x4_t){0.f, 0.f, 0.f, 0.f};

        // ---- GEMM1 (swapped): D = W1slice · E^T, pure LDS+MFMA ----
#pragma unroll
        for (int kt = 0; kt < 8; ++kt) {
            bf16x8_t ef[4];
#pragma unroll
            for (int ni = 0; ni < 4; ++ni)
                ef[ni] = *(const bf16x8_t*)(sEc + (ni * 16 + lcol) * LSTR + kt * 32 + qrow * 8);
#pragma unroll
            for (int mi = 0; mi < 4; ++mi)
#pragma unroll
                for (int ni = 0; ni < 4; ++ni)
                    acc[mi][ni] = __builtin_amdgcn_mfma_f32_16x16x32_bf16(
                        w1f[kt][mi], ef[ni], acc[mi][ni], 0, 0, 0);
        }

        // ---- epilogue 1: +b1, relu, packed bf16x4 -> sH ----
#pragma unroll
        for (int mi = 0; mi < 4; ++mi) {
            int fbase = wave * 64 + mi * 16 + qrow * 4;
            float4 bb = bias1[mi];
#pragma unroll
            for (int ni = 0; ni < 4; ++ni) {
                int m = ni * 16 + lcol;
                float v0 = acc[mi][ni][0] + bb.x;
                float v1 = acc[mi][ni][1] + bb.y;
                float v2 = acc[mi][ni][2] + bb.z;
                float v3 = acc[mi][ni][3] + bb.w;
                bf16x4_t h = { (__bf16)fmaxf(v0, 0.f), (__bf16)fmaxf(v1, 0.f),
                               (__bf16)fmaxf(v2, 0.f), (__bf16)fmaxf(v3, 0.f) };
                *(bf16x4_t*)(sH + m * LSTR + fbase) = h;
            }
        }
        __syncthreads();   // epi1 writes of sH done before any wave's GEMM2 reads

        // ---- issue gather for tile t+1 (clamped on last tile; overlaps GEMM2) ----
        int gn = blk * TPB + t + 1;
        int e_n = gn * MTILE + srow;            if (e_n >= EE) e_n = EE - 1;
        int recv_n = gn * 2 + (srow >> 5);      if (recv_n >= NN) recv_n = NN - 1;
        int send_n = senders[e_n];
        const float4* vr = (const float4*)(nf + (size_t)recv_n * CIN) + spart * 8;
        const float4* ur = (const float4*)(nf + (size_t)send_n * CIN) + spart * 8;
        float4 gv[8], gu[8];
#pragma unroll
        for (int i = 0; i < 8; ++i) { gv[i] = vr[i]; gu[i] = ur[i]; }

        // ---- GEMM2 (unswapped): D = H · W2slice, pure LDS+MFMA ----
#pragma unroll
        for (int mi = 0; mi < 4; ++mi)
#pragma unroll
            for (int ni = 0; ni < 4; ++ni)
                acc[mi][ni] = (f32x4_t){0.f, 0.f, 0.f, 0.f};
#pragma unroll
        for (int kt = 0; kt < 8; ++kt) {
            bf16x8_t af[4];
#pragma unroll
            for (int mi = 0; mi < 4; ++mi)
                af[mi] = *(const bf16x8_t*)(sH + (mi * 16 + lcol) * LSTR + kt * 32 + qrow * 8);
#pragma unroll
            for (int mi = 0; mi < 4; ++mi)
#pragma unroll
                for (int ni = 0; ni < 4; ++ni)
                    acc[mi][ni] = __builtin_amdgcn_mfma_f32_16x16x32_bf16(
                        af[mi], w2f[kt][ni], acc[mi][ni], 0, 0, 0);
        }

        // ---- write gathered tile t+1 into the other sE buffer ----
        {
            __bf16* a0 = sE + (1 - cur) * (MTILE * LSTR) + srow * LSTR + spart * 32;
#pragma unroll
            for (int i = 0; i < 8; ++i) {
                float4 v = gv[i], u = gu[i];
                bf16x4_t pv = { (__bf16)v.x, (__bf16)v.y, (__bf16)v.z, (__bf16)v.w };
                bf16x4_t pd = { (__bf16)(u.x - v.x), (__bf16)(u.y - v.y),
                                (__bf16)(u.z - v.z), (__bf16)(u.w - v.w) };
                *(bf16x4_t*)(a0 + i * 4)       = pv;
                *(bf16x4_t*)(a0 + CIN + i * 4) = pd;
            }
        }
        __syncthreads();   // sE[next] ready; sH reads done before next epi1

        // ---- epilogue 2: per-node max over 32 edge rows, +b2, store ----
        int g = blk * TPB + t;
#pragma unroll
        for (int ni = 0; ni < 4; ++ni) {
            int col = wave * 64 + ni * 16 + lcol;
#pragma unroll
            for (int node = 0; node < 2; ++node) {
                float mx = -3.402823466e38f;
#pragma unroll
                for (int mi = 0; mi < 2; ++mi)
#pragma unroll
                    for (int r = 0; r < 4; ++r)
                        mx = fmaxf(mx, acc[node * 2 + mi][ni][r]);
                mx = fmaxf(mx, __shfl_xor(mx, 16, 64));
                mx = fmaxf(mx, __shfl_xor(mx, 32, 64));
                if (qrow == 0)
                    out[(size_t)(g * 2 + node) * HD + col] = mx + b2[col];
            }
        }
        cur ^= 1;
    }
}

extern "C" void kernel_launch(void* const* d_in, const int* in_sizes, int n_in,
                              void* d_out, int out_size, void* d_ws, size_t ws_size,
                              hipStream_t stream) {
    const float* nf      = (const float*)d_in[0];
    const int*   senders = (const int*)d_in[1];
    // d_in[2] = receivers: implicit (repeat(arange(N), K)), unused
    const float* W1 = (const float*)d_in[3];
    const float* b1 = (const float*)d_in[4];
    const float* W2 = (const float*)d_in[5];
    const float* b2 = (const float*)d_in[6];

    __bf16* W1T = (__bf16*)d_ws;           // 256*256 bf16 = 128 KB
    __bf16* W2T = W1T + 256 * 256;         // next 128 KB

    ec_prep_weights<<<256, 256, 0, stream>>>(W1, W2, W1T, W2T);
    ec_main<<<NBLK, 256, 0, stream>>>(nf, senders, W1T, W2T, b1, b2, (float*)d_out);
}